// Round 8
// baseline (94.003 us; speedup 1.0000x reference)
//
#include <hip/hip_runtime.h>

#define TPB 256

// v_sin_f32 computes sin(2*pi*x) -- input in REVOLUTIONS (cdna4_isa.md §3).
// Inputs are in [0,1]: no range reduction needed.
__device__ __forceinline__ float sin2pi(float x) {
    return __builtin_amdgcn_sinf(x);
}

// diff_round(x) = x - sin(2pi x)/(2pi): one v_sin + one v_fma
__device__ __forceinline__ float diff_round(float x) {
    return __builtin_fmaf(sin2pi(x), -0.15915494309189533577f, x);
}

// One v_add_f32_dpp: v += dpp_move(v, CTRL). Pure VALU, no LDS pipe.
template <int CTRL>
__device__ __forceinline__ float dpp_add(float v) {
    int i = __float_as_int(v);
    int m = __builtin_amdgcn_update_dpp(i, i, CTRL, 0xF, 0xF, false);
    return v + __int_as_float(m);
}

// Sum across a 16-lane DPP row: 4 VALU instructions, serial-dependent.
__device__ __forceinline__ float row_sum16(float s) {
    s = dpp_add<0xB1>(s);   // quad_perm [1,0,3,2]  == xor 1
    s = dpp_add<0x4E>(s);   // quad_perm [2,3,0,1]  == xor 2
    s = dpp_add<0x124>(s);  // row_ror:4
    s = dpp_add<0x128>(s);  // row_ror:8
    return s;
}

// varr for one tile; result uniform across the 16-lane row. Four calls on
// independent tiles interleave in the scheduler (4x ILP on the ~150-cycle
// serial sin/DPP chain -- R6/R7 showed the kernel is latency-bound).
__device__ __forceinline__ float tile_varr(const float4 iv, const float4 mv) {
    float m0 = diff_round(diff_round(mv.x));
    float m1 = diff_round(diff_round(mv.y));
    float m2 = diff_round(diff_round(mv.z));
    float m3 = diff_round(diff_round(mv.w));
    float x0 = iv.x * m0, x1 = iv.y * m1, x2 = iv.z * m2, x3 = iv.w * m3;

    float sm = row_sum16((m0 + m1) + (m2 + m3));
    float sx = row_sum16((x0 + x1) + (x2 + x3));
    const float inv_msum = __builtin_amdgcn_rcpf(sm + 1e-8f);  // ~1 ulp, thr 1.5e-2
    const float mean = sx * inv_msum;

    float d0 = (x0 - mean) * m0;
    float d1 = (x1 - mean) * m1;
    float d2 = (x2 - mean) * m2;
    float d3 = (x3 - mean) * m3;
    float sd = row_sum16((d0 * d0 + d1 * d1) + (d2 * d2 + d3 * d3));
    return sd * inv_msum;
}

// Flat one-shot mapping: block covers 64 consecutive tiles, each 16-lane row
// owns 4 adjacent tiles. ALL 8 float4 loads (8 KB/wave) issue upfront before
// any compute -- per-CU bytes in flight ~128-256 KB >> the ~10 KB Little's
// law needs for 6.3 TB/s, and the 4 tile chains are fully independent.
// No grid-stride loop, no prefetch state machine (R7's 2-iteration loop
// covered only half its loads and left ~150-cycle chains 2-deep).
__global__ __launch_bounds__(TPB) void area_var4(
    const float* __restrict__ img, const float* __restrict__ msk,
    float* __restrict__ partial, int ntiles) {
    const int tid  = threadIdx.x;
    const int wave = tid >> 6;      // 0..3
    const int lane = tid & 63;
    const int grp  = lane >> 4;     // DPP row within wave
    const int j    = lane & 15;     // float4 index within tile

    // Row's first tile: 4 adjacent tiles per row.
    const int t0 = blockIdx.x * 64 + (wave * 4 + grp) * 4;

    float4 iv[4], mv[4];
    #pragma unroll
    for (int k = 0; k < 4; ++k) {   // 8 global_load_dwordx4, all independent
        iv[k] = make_float4(0.f, 0.f, 0.f, 0.f);
        mv[k] = make_float4(0.f, 0.f, 0.f, 0.f);
        if (t0 + k < ntiles) {
            const size_t off = (size_t)(t0 + k) * 64 + (size_t)j * 4;
            iv[k] = *reinterpret_cast<const float4*>(img + off);
            mv[k] = *reinterpret_cast<const float4*>(msk + off);
        }
    }

    // Four independent varr chains; compiler interleaves them.
    float acc = tile_varr(iv[0], mv[0]);
    acc += tile_varr(iv[1], mv[1]);
    acc += tile_varr(iv[2], mv[2]);
    acc += tile_varr(iv[3], mv[3]);

    // acc uniform per row; sum the wave's 4 rows, then the block's 4 waves.
    acc += __shfl_xor(acc, 16, 64);
    acc += __shfl_xor(acc, 32, 64);

    __shared__ float wsum[TPB / 64];
    if (lane == 0) wsum[wave] = acc;
    __syncthreads();
    if (tid == 0) partial[blockIdx.x] = (wsum[0] + wsum[1]) + (wsum[2] + wsum[3]);
}

__global__ __launch_bounds__(TPB) void final_reduce(
    const float* __restrict__ partial, float* __restrict__ out,
    int n, float inv_count) {
    float s = 0.f;
    for (int i = threadIdx.x; i < n; i += TPB) s += partial[i];
    #pragma unroll
    for (int d = 1; d < 64; d <<= 1) s += __shfl_xor(s, d, 64);
    __shared__ float wsum[TPB / 64];
    const int wave = threadIdx.x >> 6;
    const int lane = threadIdx.x & 63;
    if (lane == 0) wsum[wave] = s;
    __syncthreads();
    if (threadIdx.x == 0)
        out[0] = ((wsum[0] + wsum[1]) + (wsum[2] + wsum[3])) * inv_count;
}

extern "C" void kernel_launch(void* const* d_in, const int* in_sizes, int n_in,
                              void* d_out, int out_size, void* d_ws, size_t ws_size,
                              hipStream_t stream) {
    const float* img = (const float*)d_in[0];   // sv_area_image [B,N,P,Q] fp32
    const float* msk = (const float*)d_in[1];   // sv_area_mask  [B,N,P,Q] fp32
    float* out = (float*)d_out;                 // scalar fp32
    float* partial = (float*)d_ws;

    const int ntiles = in_sizes[0] / 64;        // B*N = 131072
    const int nblocks = (ntiles + 63) / 64;     // 2048 -- exact one-shot fit

    area_var4<<<nblocks, TPB, 0, stream>>>(img, msk, partial, ntiles);
    final_reduce<<<1, TPB, 0, stream>>>(partial, out, nblocks,
                                        1.0f / (float)ntiles);
}